// Round 3
// baseline (423.075 us; speedup 1.0000x reference)
//
#include <hip/hip_runtime.h>
#include <math.h>

// SGC: out = log_softmax((A_hat^2 x) W + b), A_hat = D^-1/2 (A+I) D^-1/2
// Propagate in 40-dim class space: (A^2 X) W == A^2 (X W).
// Z = D^-1/2 Y substitution: Z' = di^2 (sum_s Z_s + Z_i)  -> pure gather-add.
// Z stored chunk-major Z[c4][node] (float4); each hop = 5 passes of 8 classes
// (3.2 MB footprint, fits per-XCD 4MB L2). Hops interleaved per chunk for
// L2-dirty-hot reuse.

#define FDIM 128
#define CDIM 40
#define C4   10    // CDIM/4
#define BKT_SHIFT 8
#define NB   512   // bucket slots (>= ceil(N/256))
#define NBLK 512   // edge-partition blocks

// ---- pass 1: per-block histogram over dst buckets (LDS, no global atomics)
__global__ void hist_k(const int* __restrict__ dst, int* __restrict__ G,
                       int E, int EB) {
    __shared__ int h[NB];
    int t = threadIdx.x;
    for (int i = t; i < NB; i += 256) h[i] = 0;
    __syncthreads();
    int s = blockIdx.x * EB;
    int e = min(s + EB, E);
    for (int i = s + t; i < e; i += 256)
        atomicAdd(&h[dst[i] >> BKT_SHIFT], 1);
    __syncthreads();
    for (int i = t; i < NB; i += 256) G[blockIdx.x * NB + i] = h[i];
}

// ---- pass 2: per-bucket exclusive scan over blocks (in-place on G); totals->T
__global__ void colscan_k(int* __restrict__ G, int* __restrict__ T) {
    __shared__ int lds[256];
    int j = blockIdx.x;
    int t = threadIdx.x;
    int v0 = G[(2 * t) * NB + j];
    int v1 = G[(2 * t + 1) * NB + j];
    int s = v0 + v1;
    lds[t] = s;
    __syncthreads();
    for (int off = 1; off < 256; off <<= 1) {
        int a = (t >= off) ? lds[t - off] : 0;
        __syncthreads();
        lds[t] += a;
        __syncthreads();
    }
    int excl = lds[t] - s;
    G[(2 * t) * NB + j] = excl;
    G[(2 * t + 1) * NB + j] = excl + v0;
    if (t == 255) T[j] = lds[255];
}

// ---- pass 2b: exclusive scan of bucket totals -> bs[0..NB], bs[NB]=E
__global__ void bscan_k(const int* __restrict__ T, int* __restrict__ bs) {
    __shared__ int lds[256];
    int t = threadIdx.x;
    int v0 = T[2 * t];
    int v1 = T[2 * t + 1];
    int s = v0 + v1;
    lds[t] = s;
    __syncthreads();
    for (int off = 1; off < 256; off <<= 1) {
        int a = (t >= off) ? lds[t - off] : 0;
        __syncthreads();
        lds[t] += a;
        __syncthreads();
    }
    int excl = lds[t] - s;
    bs[2 * t] = excl;
    bs[2 * t + 1] = excl + v0;
    if (t == 255) bs[NB] = lds[255];
}

// ---- pass 3: scatter packed edges into bucket-partitioned tmp
// pack: src (24 bits) | dstLocal (8 bits) << 24   [requires N < 2^24]
__global__ void part_k(const int* __restrict__ src, const int* __restrict__ dst,
                       const int* __restrict__ G, const int* __restrict__ bs,
                       unsigned int* __restrict__ tmp, int E, int EB) {
    __shared__ int offs[NB];
    __shared__ int cur[NB];
    int t = threadIdx.x;
    for (int i = t; i < NB; i += 256) {
        offs[i] = bs[i] + G[blockIdx.x * NB + i];
        cur[i] = 0;
    }
    __syncthreads();
    int s = blockIdx.x * EB;
    int e = min(s + EB, E);
    for (int i = s + t; i < e; i += 256) {
        int d = dst[i];
        int j = d >> BKT_SHIFT;
        int r = atomicAdd(&cur[j], 1);
        tmp[offs[j] + r] = (unsigned int)src[i] | ((unsigned int)(d & 255) << 24);
    }
}

// ---- pass 4: one block per bucket: rowptr/dinv/dsq + CSR col fill (all local)
__global__ void csr_k(const unsigned int* __restrict__ tmp, const int* __restrict__ bs,
                      int* __restrict__ rowptr, float* __restrict__ dinv,
                      float* __restrict__ dsq, int* __restrict__ col, int N, int E) {
    __shared__ int cnt[256];
    __shared__ int ptr[256];
    int j = blockIdx.x;
    int t = threadIdx.x;
    int base = j << BKT_SHIFT;
    int s = bs[j];
    int e = bs[j + 1];
    cnt[t] = 0;
    __syncthreads();
    for (int i = s + t; i < e; i += 256)
        atomicAdd(&cnt[tmp[i] >> 24], 1);
    __syncthreads();
    int v = cnt[t];
    ptr[t] = v;
    __syncthreads();
    for (int off = 1; off < 256; off <<= 1) {
        int a = (t >= off) ? ptr[t - off] : 0;
        __syncthreads();
        ptr[t] += a;
        __syncthreads();
    }
    int excl = ptr[t] - v;
    int node = base + t;
    if (node < N) {
        rowptr[node] = s + excl;
        float d = (float)(v + 1);              // +1 self-loop
        dinv[node] = rsqrtf(d);
        dsq[node] = sqrtf(d);
    }
    if (j == 0 && t == 0) rowptr[N] = E;
    cnt[t] = excl;  // cursor
    __syncthreads();
    for (int i = s + t; i < e; i += 256) {
        unsigned int p = tmp[i];
        int loc = p >> 24;
        int r = atomicAdd(&cnt[loc], 1);
        col[s + r] = (int)(p & 0xFFFFFF);
    }
}

// ---- Z0[c4][node] = dinv[node] * (x[node] @ W)[c4 block]; W staged in LDS.
__global__ void gemm_k(const float* __restrict__ x, const float* __restrict__ W,
                       const float* __restrict__ dinv, float4* __restrict__ Z, int n) {
    __shared__ float Ws[FDIM * CDIM];
    for (int i = threadIdx.x; i < FDIM * CDIM; i += 256) Ws[i] = W[i];
    __syncthreads();
    int gid = blockIdx.x * 256 + threadIdx.x;
    int node = gid / C4;
    int c4 = gid % C4;
    if (node >= n) return;
    const float4* xr = (const float4*)(x + (size_t)node * FDIM);
    float4 acc = make_float4(0.f, 0.f, 0.f, 0.f);
    #pragma unroll 8
    for (int f4 = 0; f4 < FDIM / 4; ++f4) {
        float4 xv = xr[f4];
        const float* wb = &Ws[(f4 * 4) * CDIM + c4 * 4];
        float4 w0 = *(const float4*)(wb);
        float4 w1 = *(const float4*)(wb + CDIM);
        float4 w2 = *(const float4*)(wb + 2 * CDIM);
        float4 w3 = *(const float4*)(wb + 3 * CDIM);
        acc.x += xv.x * w0.x + xv.y * w1.x + xv.z * w2.x + xv.w * w3.x;
        acc.y += xv.x * w0.y + xv.y * w1.y + xv.z * w2.y + xv.w * w3.y;
        acc.z += xv.x * w0.z + xv.y * w1.z + xv.z * w2.z + xv.w * w3.z;
        acc.w += xv.x * w0.w + xv.y * w1.w + xv.z * w2.w + xv.w * w3.w;
    }
    float di = dinv[node];
    Z[(size_t)c4 * n + node] = make_float4(acc.x * di, acc.y * di, acc.z * di, acc.w * di);
}

// ---- one chunk-pass of one hop: Zout[c4][i] = di^2 (sum_{s->i} Zin[c4][s] + Zin[c4][i])
// 2 lanes per node (c4base, c4base+1); pure gather-add, unroll 4.
__global__ void prop_k(const int* __restrict__ rowptr, const int* __restrict__ col,
                       const float* __restrict__ dinv, const float4* __restrict__ Zin,
                       float4* __restrict__ Zout, int n, int c4base) {
    int gid = blockIdx.x * 256 + threadIdx.x;
    int node = gid >> 1;
    if (node >= n) return;
    int c4 = c4base + (gid & 1);
    const float4* Zc = Zin + (size_t)c4 * n;
    float di = dinv[node];
    float4 acc = Zc[node];  // self-loop
    int e = rowptr[node];
    int end = rowptr[node + 1];
    for (; e + 3 < end; e += 4) {
        int s0 = col[e], s1 = col[e + 1], s2 = col[e + 2], s3 = col[e + 3];
        float4 a0 = Zc[s0], a1 = Zc[s1], a2 = Zc[s2], a3 = Zc[s3];
        acc.x += (a0.x + a1.x) + (a2.x + a3.x);
        acc.y += (a0.y + a1.y) + (a2.y + a3.y);
        acc.z += (a0.z + a1.z) + (a2.z + a3.z);
        acc.w += (a0.w + a1.w) + (a2.w + a3.w);
    }
    for (; e < end; ++e) {
        int s = col[e];
        float4 a = Zc[s];
        acc.x += a.x; acc.y += a.y; acc.z += a.z; acc.w += a.w;
    }
    float w = di * di;
    Zout[(size_t)c4 * n + node] = make_float4(acc.x * w, acc.y * w, acc.z * w, acc.w * w);
}

// ---- final: logits = Z2[i]*dsq[i] + b; log_softmax; thread-per-node.
__global__ void final_k(const float4* __restrict__ Z, const float* __restrict__ dsq,
                        const float* __restrict__ bias, float4* __restrict__ out, int n) {
    __shared__ float bsm[CDIM];
    int t = threadIdx.x;
    if (t < CDIM) bsm[t] = bias[t];
    __syncthreads();
    int node = blockIdx.x * 256 + t;
    if (node >= n) return;
    float ds = dsq[node];
    float v[CDIM];
    #pragma unroll
    for (int c4 = 0; c4 < C4; ++c4) {
        float4 z = Z[(size_t)c4 * n + node];
        v[c4 * 4 + 0] = z.x * ds + bsm[c4 * 4 + 0];
        v[c4 * 4 + 1] = z.y * ds + bsm[c4 * 4 + 1];
        v[c4 * 4 + 2] = z.z * ds + bsm[c4 * 4 + 2];
        v[c4 * 4 + 3] = z.w * ds + bsm[c4 * 4 + 3];
    }
    float m = v[0];
    #pragma unroll
    for (int c = 1; c < CDIM; ++c) m = fmaxf(m, v[c]);
    float s = 0.f;
    #pragma unroll
    for (int c = 0; c < CDIM; ++c) s += expf(v[c] - m);
    float ls = m + logf(s);
    #pragma unroll
    for (int c4 = 0; c4 < C4; ++c4) {
        out[(size_t)node * C4 + c4] = make_float4(
            v[c4 * 4 + 0] - ls, v[c4 * 4 + 1] - ls,
            v[c4 * 4 + 2] - ls, v[c4 * 4 + 3] - ls);
    }
}

extern "C" void kernel_launch(void* const* d_in, const int* in_sizes, int n_in,
                              void* d_out, int out_size, void* d_ws, size_t ws_size,
                              hipStream_t stream) {
    const float* x = (const float*)d_in[0];
    const float* W = (const float*)d_in[1];
    const float* b = (const float*)d_in[2];
    const int* ei = (const int*)d_in[3];

    int C = in_sizes[2];            // 40
    int F = in_sizes[1] / C;        // 128
    int N = in_sizes[0] / F;        // 100000
    int E = in_sizes[3] / 2;        // 1600000
    const int* src = ei;
    const int* dst = ei + E;

    // workspace: union region holds {G,T,bs,tmp} during build, then Za (16MB).
    char* ws = (char*)d_ws;
    size_t goff = 0;
    int* G = (int*)(ws + goff);                       goff += (size_t)NBLK * NB * 4;
    int* T = (int*)(ws + goff);                       goff += (size_t)NB * 4;
    int* bs = (int*)(ws + goff);                      goff += (size_t)(NB + 1) * 4 + 12;
    goff = (goff + 15) & ~(size_t)15;
    unsigned int* tmp = (unsigned int*)(ws + goff);   goff += (size_t)E * 4;
    size_t unionEnd = ((size_t)N * CDIM * 4 > goff) ? (size_t)N * CDIM * 4 : goff;
    unionEnd = (unionEnd + 15) & ~(size_t)15;
    float4* Za = (float4*)ws;                         // overlays build scratch
    size_t off = unionEnd;
    int* rowptr = (int*)(ws + off); off += ((size_t)(N + 1) * 4 + 15) & ~(size_t)15;
    float* dinv = (float*)(ws + off); off += ((size_t)N * 4 + 15) & ~(size_t)15;
    float* dsq = (float*)(ws + off); off += ((size_t)N * 4 + 15) & ~(size_t)15;
    int* col = (int*)(ws + off); off += ((size_t)E * 4 + 15) & ~(size_t)15;
    float4* Zb = (float4*)d_out;                      // hop-1 ping buffer

    int EB = (E + NBLK - 1) / NBLK;
    int NBr = (N + 255) >> BKT_SHIFT;

    hist_k<<<NBLK, 256, 0, stream>>>(dst, G, E, EB);
    colscan_k<<<NB, 256, 0, stream>>>(G, T);
    bscan_k<<<1, 256, 0, stream>>>(T, bs);
    part_k<<<NBLK, 256, 0, stream>>>(src, dst, G, bs, tmp, E, EB);
    csr_k<<<NBr, 256, 0, stream>>>(tmp, bs, rowptr, dinv, dsq, col, N, E);

    gemm_k<<<(N * C4 + 255) / 256, 256, 0, stream>>>(x, W, dinv, Za, N);

    // per 8-class chunk: hop1 Za->Zb, hop2 Zb->Za (L2-dirty-hot reuse)
    int pb = (2 * N + 255) / 256;
    for (int p = 0; p < 5; ++p) {
        prop_k<<<pb, 256, 0, stream>>>(rowptr, col, dinv, Za, Zb, N, 2 * p);
        prop_k<<<pb, 256, 0, stream>>>(rowptr, col, dinv, Zb, Za, N, 2 * p);
    }

    final_k<<<(N + 255) / 256, 256, 0, stream>>>(Za, dsq, b, (float4*)d_out, N);
}

// Round 4
// 289.715 us; speedup vs baseline: 1.4603x; 1.4603x over previous
//
#include <hip/hip_runtime.h>
#include <math.h>

// SGC: out = log_softmax((A_hat^2 x) W + b), A_hat = D^-1/2 (A+I) D^-1/2
// (A^2 X) W == A^2 (X W): propagate in 40-dim class space.
// Z = D^-1/2 Y substitution: Z' = di^2 (sum_s Z_s + Z_i) -> pure gather-add,
// no per-edge weight gather. Z node-major [node][40] so each edge gather is
// one 160B row (~2.75 lines) -- minimal lines/edge (round-3 chunking was 4x
// worse: 16B accesses still fetch 64B lines).
// gemm: register-blocked 4 nodes x 8 classes per thread; x staged transposed
// in LDS; W reads wave-uniform (LDS broadcast). Fixes round-3's LDS-read-
// throughput bound (every FMA operand from LDS).

#define FDIM 128
#define CDIM 40
#define C4   10    // CDIM/4
#define BKT_SHIFT 8
#define NB   512   // bucket slots (>= ceil(N/256))
#define NBLK 512   // edge-partition blocks

// ---- pass 1: per-block histogram over dst buckets (LDS, no global atomics)
__global__ void hist_k(const int* __restrict__ dst, int* __restrict__ G,
                       int E, int EB) {
    __shared__ int h[NB];
    int t = threadIdx.x;
    for (int i = t; i < NB; i += 256) h[i] = 0;
    __syncthreads();
    int s = blockIdx.x * EB;
    int e = min(s + EB, E);
    for (int i = s + t; i < e; i += 256)
        atomicAdd(&h[dst[i] >> BKT_SHIFT], 1);
    __syncthreads();
    for (int i = t; i < NB; i += 256) G[blockIdx.x * NB + i] = h[i];
}

// ---- pass 2: per-bucket exclusive scan over blocks (in-place on G); totals->T
__global__ void colscan_k(int* __restrict__ G, int* __restrict__ T) {
    __shared__ int lds[256];
    int j = blockIdx.x;
    int t = threadIdx.x;
    int v0 = G[(2 * t) * NB + j];
    int v1 = G[(2 * t + 1) * NB + j];
    int s = v0 + v1;
    lds[t] = s;
    __syncthreads();
    for (int off = 1; off < 256; off <<= 1) {
        int a = (t >= off) ? lds[t - off] : 0;
        __syncthreads();
        lds[t] += a;
        __syncthreads();
    }
    int excl = lds[t] - s;
    G[(2 * t) * NB + j] = excl;
    G[(2 * t + 1) * NB + j] = excl + v0;
    if (t == 255) T[j] = lds[255];
}

// ---- pass 2b: exclusive scan of bucket totals -> bs[0..NB], bs[NB]=E
__global__ void bscan_k(const int* __restrict__ T, int* __restrict__ bs) {
    __shared__ int lds[256];
    int t = threadIdx.x;
    int v0 = T[2 * t];
    int v1 = T[2 * t + 1];
    int s = v0 + v1;
    lds[t] = s;
    __syncthreads();
    for (int off = 1; off < 256; off <<= 1) {
        int a = (t >= off) ? lds[t - off] : 0;
        __syncthreads();
        lds[t] += a;
        __syncthreads();
    }
    int excl = lds[t] - s;
    bs[2 * t] = excl;
    bs[2 * t + 1] = excl + v0;
    if (t == 255) bs[NB] = lds[255];
}

// ---- pass 3: scatter packed edges into bucket-partitioned tmp
// pack: src (24 bits) | dstLocal (8 bits) << 24   [requires N < 2^24]
__global__ void part_k(const int* __restrict__ src, const int* __restrict__ dst,
                       const int* __restrict__ G, const int* __restrict__ bs,
                       unsigned int* __restrict__ tmp, int E, int EB) {
    __shared__ int offs[NB];
    __shared__ int cur[NB];
    int t = threadIdx.x;
    for (int i = t; i < NB; i += 256) {
        offs[i] = bs[i] + G[blockIdx.x * NB + i];
        cur[i] = 0;
    }
    __syncthreads();
    int s = blockIdx.x * EB;
    int e = min(s + EB, E);
    for (int i = s + t; i < e; i += 256) {
        int d = dst[i];
        int j = d >> BKT_SHIFT;
        int r = atomicAdd(&cur[j], 1);
        tmp[offs[j] + r] = (unsigned int)src[i] | ((unsigned int)(d & 255) << 24);
    }
}

// ---- pass 4: one block per bucket: rowptr/dinv/dsq + CSR col fill (all local)
__global__ void csr_k(const unsigned int* __restrict__ tmp, const int* __restrict__ bs,
                      int* __restrict__ rowptr, float* __restrict__ dinv,
                      float* __restrict__ dsq, int* __restrict__ col, int N, int E) {
    __shared__ int cnt[256];
    __shared__ int ptr[256];
    int j = blockIdx.x;
    int t = threadIdx.x;
    int base = j << BKT_SHIFT;
    int s = bs[j];
    int e = bs[j + 1];
    cnt[t] = 0;
    __syncthreads();
    for (int i = s + t; i < e; i += 256)
        atomicAdd(&cnt[tmp[i] >> 24], 1);
    __syncthreads();
    int v = cnt[t];
    ptr[t] = v;
    __syncthreads();
    for (int off = 1; off < 256; off <<= 1) {
        int a = (t >= off) ? ptr[t - off] : 0;
        __syncthreads();
        ptr[t] += a;
        __syncthreads();
    }
    int excl = ptr[t] - v;
    int node = base + t;
    if (node < N) {
        rowptr[node] = s + excl;
        float d = (float)(v + 1);              // +1 self-loop
        dinv[node] = rsqrtf(d);
        dsq[node] = sqrtf(d);
    }
    if (j == 0 && t == 0) rowptr[N] = E;
    cnt[t] = excl;  // cursor
    __syncthreads();
    for (int i = s + t; i < e; i += 256) {
        unsigned int p = tmp[i];
        int loc = p >> 24;
        int r = atomicAdd(&cnt[loc], 1);
        col[s + r] = (int)(p & 0xFFFFFF);
    }
}

// ---- Z0[node][40] = dinv[node] * (x[node] @ W)
// 320 threads / 256-node tile; thread tile = 4 nodes x 8 classes.
// x staged transposed in LDS (xT[f][node], pad 257 -> <=2-way conflicts);
// W rows wave-uniform (cg constant per wave) -> LDS broadcast.
__global__ __launch_bounds__(320) void gemm_k(const float* __restrict__ x,
                                              const float* __restrict__ W,
                                              const float* __restrict__ dinv,
                                              float* __restrict__ Z, int n) {
    __shared__ float Ws[FDIM * CDIM];   // 20 KB
    __shared__ float xT[32][257];       // 32.9 KB
    int t = threadIdx.x;
    for (int i = t; i < FDIM * CDIM; i += 320) Ws[i] = W[i];
    int base = blockIdx.x * 256;
    int cg = t >> 6;   // 0..4 (8 classes each)
    int ng = t & 63;   // node subgroup; nodes {ng+64k}
    float acc[4][8];
    #pragma unroll
    for (int k = 0; k < 4; ++k)
        #pragma unroll
        for (int c = 0; c < 8; ++c) acc[k][c] = 0.f;

    for (int ch = 0; ch < 4; ++ch) {
        __syncthreads();
        for (int i = t; i < 2048; i += 320) {
            int f4 = i & 7;
            int nn = i >> 3;
            int node = base + nn;
            float4 xv = make_float4(0.f, 0.f, 0.f, 0.f);
            if (node < n)
                xv = *(const float4*)(x + (size_t)node * FDIM + ch * 32 + f4 * 4);
            xT[f4 * 4 + 0][nn] = xv.x;
            xT[f4 * 4 + 1][nn] = xv.y;
            xT[f4 * 4 + 2][nn] = xv.z;
            xT[f4 * 4 + 3][nn] = xv.w;
        }
        __syncthreads();
        for (int f = 0; f < 32; ++f) {
            float x0 = xT[f][ng];
            float x1 = xT[f][ng + 64];
            float x2 = xT[f][ng + 128];
            float x3 = xT[f][ng + 192];
            const float* wr = &Ws[(ch * 32 + f) * CDIM + cg * 8];
            float4 w0 = *(const float4*)(wr);
            float4 w1 = *(const float4*)(wr + 4);
            float wv[8] = {w0.x, w0.y, w0.z, w0.w, w1.x, w1.y, w1.z, w1.w};
            #pragma unroll
            for (int c = 0; c < 8; ++c) {
                acc[0][c] += x0 * wv[c];
                acc[1][c] += x1 * wv[c];
                acc[2][c] += x2 * wv[c];
                acc[3][c] += x3 * wv[c];
            }
        }
    }
    #pragma unroll
    for (int k = 0; k < 4; ++k) {
        int node = base + ng + 64 * k;
        if (node >= n) continue;
        float di = dinv[node];
        float4 o0 = make_float4(acc[k][0] * di, acc[k][1] * di,
                                acc[k][2] * di, acc[k][3] * di);
        float4 o1 = make_float4(acc[k][4] * di, acc[k][5] * di,
                                acc[k][6] * di, acc[k][7] * di);
        *(float4*)(Z + (size_t)node * CDIM + cg * 8) = o0;
        *(float4*)(Z + (size_t)node * CDIM + cg * 8 + 4) = o1;
    }
}

// ---- one hop: Zout[i] = di^2 (sum_{s->i} Zin[s] + Zin[i])
// 10 lanes per node (one float4 of classes each); 25 nodes / 256-thread block.
// Pure gather-add, unroll 4 for MLP.
__global__ __launch_bounds__(256) void prop_k(const int* __restrict__ rowptr,
                                              const int* __restrict__ col,
                                              const float* __restrict__ dinv,
                                              const float4* __restrict__ Zin,
                                              float4* __restrict__ Zout, int n) {
    int t = threadIdx.x;
    int g = t / C4;
    int c4 = t % C4;
    int node = blockIdx.x * 25 + g;
    if (g >= 25 || node >= n) return;
    float di = dinv[node];
    float4 acc = Zin[(size_t)node * C4 + c4];   // self-loop
    int e = rowptr[node];
    int end = rowptr[node + 1];
    for (; e + 3 < end; e += 4) {
        int s0 = col[e], s1 = col[e + 1], s2 = col[e + 2], s3 = col[e + 3];
        float4 a0 = Zin[(size_t)s0 * C4 + c4];
        float4 a1 = Zin[(size_t)s1 * C4 + c4];
        float4 a2 = Zin[(size_t)s2 * C4 + c4];
        float4 a3 = Zin[(size_t)s3 * C4 + c4];
        acc.x += (a0.x + a1.x) + (a2.x + a3.x);
        acc.y += (a0.y + a1.y) + (a2.y + a3.y);
        acc.z += (a0.z + a1.z) + (a2.z + a3.z);
        acc.w += (a0.w + a1.w) + (a2.w + a3.w);
    }
    for (; e < end; ++e) {
        int s = col[e];
        float4 a = Zin[(size_t)s * C4 + c4];
        acc.x += a.x; acc.y += a.y; acc.z += a.z; acc.w += a.w;
    }
    float w = di * di;
    Zout[(size_t)node * C4 + c4] = make_float4(acc.x * w, acc.y * w,
                                               acc.z * w, acc.w * w);
}

// ---- final: logits = Z2[i]*dsq[i] + b; log_softmax; thread-per-node.
__global__ void final_k(const float4* __restrict__ Z, const float* __restrict__ dsq,
                        const float* __restrict__ bias, float4* __restrict__ out, int n) {
    __shared__ float bsm[CDIM];
    int t = threadIdx.x;
    if (t < CDIM) bsm[t] = bias[t];
    __syncthreads();
    int node = blockIdx.x * 256 + t;
    if (node >= n) return;
    float ds = dsq[node];
    float v[CDIM];
    #pragma unroll
    for (int c4 = 0; c4 < C4; ++c4) {
        float4 z = Z[(size_t)node * C4 + c4];
        v[c4 * 4 + 0] = z.x * ds + bsm[c4 * 4 + 0];
        v[c4 * 4 + 1] = z.y * ds + bsm[c4 * 4 + 1];
        v[c4 * 4 + 2] = z.z * ds + bsm[c4 * 4 + 2];
        v[c4 * 4 + 3] = z.w * ds + bsm[c4 * 4 + 3];
    }
    float m = v[0];
    #pragma unroll
    for (int c = 1; c < CDIM; ++c) m = fmaxf(m, v[c]);
    float s = 0.f;
    #pragma unroll
    for (int c = 0; c < CDIM; ++c) s += expf(v[c] - m);
    float ls = m + logf(s);
    #pragma unroll
    for (int c4 = 0; c4 < C4; ++c4) {
        out[(size_t)node * C4 + c4] = make_float4(
            v[c4 * 4 + 0] - ls, v[c4 * 4 + 1] - ls,
            v[c4 * 4 + 2] - ls, v[c4 * 4 + 3] - ls);
    }
}

extern "C" void kernel_launch(void* const* d_in, const int* in_sizes, int n_in,
                              void* d_out, int out_size, void* d_ws, size_t ws_size,
                              hipStream_t stream) {
    const float* x = (const float*)d_in[0];
    const float* W = (const float*)d_in[1];
    const float* b = (const float*)d_in[2];
    const int* ei = (const int*)d_in[3];

    int C = in_sizes[2];            // 40
    int F = in_sizes[1] / C;        // 128
    int N = in_sizes[0] / F;        // 100000
    int E = in_sizes[3] / 2;        // 1600000
    const int* src = ei;
    const int* dst = ei + E;

    // workspace: union region holds {G,T,bs,tmp} during build, then Za (16MB).
    char* ws = (char*)d_ws;
    size_t goff = 0;
    int* G = (int*)(ws + goff);                       goff += (size_t)NBLK * NB * 4;
    int* T = (int*)(ws + goff);                       goff += (size_t)NB * 4;
    int* bs = (int*)(ws + goff);                      goff += (size_t)(NB + 1) * 4 + 12;
    goff = (goff + 15) & ~(size_t)15;
    unsigned int* tmp = (unsigned int*)(ws + goff);   goff += (size_t)E * 4;
    size_t unionEnd = ((size_t)N * CDIM * 4 > goff) ? (size_t)N * CDIM * 4 : goff;
    unionEnd = (unionEnd + 15) & ~(size_t)15;
    float* Za = (float*)ws;                           // overlays build scratch
    size_t off = unionEnd;
    int* rowptr = (int*)(ws + off); off += ((size_t)(N + 1) * 4 + 15) & ~(size_t)15;
    float* dinv = (float*)(ws + off); off += ((size_t)N * 4 + 15) & ~(size_t)15;
    float* dsq = (float*)(ws + off); off += ((size_t)N * 4 + 15) & ~(size_t)15;
    int* col = (int*)(ws + off); off += ((size_t)E * 4 + 15) & ~(size_t)15;
    float4* Zb = (float4*)d_out;                      // hop-1 ping buffer

    int EB = (E + NBLK - 1) / NBLK;
    int NBr = (N + 255) >> BKT_SHIFT;

    hist_k<<<NBLK, 256, 0, stream>>>(dst, G, E, EB);
    colscan_k<<<NB, 256, 0, stream>>>(G, T);
    bscan_k<<<1, 256, 0, stream>>>(T, bs);
    part_k<<<NBLK, 256, 0, stream>>>(src, dst, G, bs, tmp, E, EB);
    csr_k<<<NBr, 256, 0, stream>>>(tmp, bs, rowptr, dinv, dsq, col, N, E);

    gemm_k<<<(N + 255) / 256, 320, 0, stream>>>(x, W, dinv, Za, N);

    prop_k<<<(N + 24) / 25, 256, 0, stream>>>(rowptr, col, dinv, (const float4*)Za, Zb, N);
    prop_k<<<(N + 24) / 25, 256, 0, stream>>>(rowptr, col, dinv, (const float4*)Zb, (float4*)Za, N);

    final_k<<<(N + 255) / 256, 256, 0, stream>>>((const float4*)Za, dsq, b, (float4*)d_out, N);
}

// Round 5
// 252.502 us; speedup vs baseline: 1.6755x; 1.1474x over previous
//
#include <hip/hip_runtime.h>
#include <math.h>

// SGC: out = log_softmax((A_hat^2 x) W + b), A_hat = D^-1/2 (A+I) D^-1/2
// (A^2 X) W == A^2 (X W): propagate in 40-dim class space.
// Z = D^-1/2 Y: Z' = di^2 (sum_s Z_s + Z_i) -> pure gather-add.
// Round-5: gathered Z buffers stored bf16 (80 B rows = exactly 2 lines/edge,
// 8 MB footprint) because prop is pinned at ~3.2 TB/s on the L2-miss path
// (rounds 2+4 both). Accumulate fp32; hop-2 output fp32 (streamed only).
// 5 lanes/node x uint4 (8 bf16) per gather.

#define FDIM 128
#define CDIM 40
#define C4   10
#define BKT_SHIFT 8
#define NB   512   // bucket slots (>= ceil(N/256))
#define NBLK 512   // edge-partition blocks
#define NPB  51    // nodes per 256-thread prop block (5 lanes/node)

// ---------- bf16 helpers (RTNE pack; finite inputs) ----------
__device__ __forceinline__ unsigned int bf16rn(float f) {
    unsigned int u = __float_as_uint(f);
    return (u + 0x7fffu + ((u >> 16) & 1u)) >> 16;
}
__device__ __forceinline__ unsigned int pack2(float lo, float hi) {
    unsigned int a = bf16rn(lo);
    unsigned int b = __float_as_uint(hi);
    b = (b + 0x7fffu + ((b >> 16) & 1u)) & 0xffff0000u;
    return a | b;
}
__device__ __forceinline__ void addu4(uint4 u, float* a) {
    a[0] += __uint_as_float(u.x << 16);
    a[1] += __uint_as_float(u.x & 0xffff0000u);
    a[2] += __uint_as_float(u.y << 16);
    a[3] += __uint_as_float(u.y & 0xffff0000u);
    a[4] += __uint_as_float(u.z << 16);
    a[5] += __uint_as_float(u.z & 0xffff0000u);
    a[6] += __uint_as_float(u.w << 16);
    a[7] += __uint_as_float(u.w & 0xffff0000u);
}

// ---- pass 1: per-block histogram over dst buckets (LDS, no global atomics)
__global__ void hist_k(const int* __restrict__ dst, int* __restrict__ G,
                       int E, int EB) {
    __shared__ int h[NB];
    int t = threadIdx.x;
    for (int i = t; i < NB; i += 256) h[i] = 0;
    __syncthreads();
    int s = blockIdx.x * EB;
    int e = min(s + EB, E);
    for (int i = s + t; i < e; i += 256)
        atomicAdd(&h[dst[i] >> BKT_SHIFT], 1);
    __syncthreads();
    for (int i = t; i < NB; i += 256) G[blockIdx.x * NB + i] = h[i];
}

// ---- pass 2: per-bucket exclusive scan over blocks (in-place on G); totals->T
__global__ void colscan_k(int* __restrict__ G, int* __restrict__ T) {
    __shared__ int lds[256];
    int j = blockIdx.x;
    int t = threadIdx.x;
    int v0 = G[(2 * t) * NB + j];
    int v1 = G[(2 * t + 1) * NB + j];
    int s = v0 + v1;
    lds[t] = s;
    __syncthreads();
    for (int off = 1; off < 256; off <<= 1) {
        int a = (t >= off) ? lds[t - off] : 0;
        __syncthreads();
        lds[t] += a;
        __syncthreads();
    }
    int excl = lds[t] - s;
    G[(2 * t) * NB + j] = excl;
    G[(2 * t + 1) * NB + j] = excl + v0;
    if (t == 255) T[j] = lds[255];
}

// ---- pass 2b: exclusive scan of bucket totals -> bs[0..NB], bs[NB]=E
__global__ void bscan_k(const int* __restrict__ T, int* __restrict__ bs) {
    __shared__ int lds[256];
    int t = threadIdx.x;
    int v0 = T[2 * t];
    int v1 = T[2 * t + 1];
    int s = v0 + v1;
    lds[t] = s;
    __syncthreads();
    for (int off = 1; off < 256; off <<= 1) {
        int a = (t >= off) ? lds[t - off] : 0;
        __syncthreads();
        lds[t] += a;
        __syncthreads();
    }
    int excl = lds[t] - s;
    bs[2 * t] = excl;
    bs[2 * t + 1] = excl + v0;
    if (t == 255) bs[NB] = lds[255];
}

// ---- pass 3: scatter packed edges into bucket-partitioned tmp
// pack: src (24 bits) | dstLocal (8 bits) << 24   [requires N < 2^24]
__global__ void part_k(const int* __restrict__ src, const int* __restrict__ dst,
                       const int* __restrict__ G, const int* __restrict__ bs,
                       unsigned int* __restrict__ tmp, int E, int EB) {
    __shared__ int offs[NB];
    __shared__ int cur[NB];
    int t = threadIdx.x;
    for (int i = t; i < NB; i += 256) {
        offs[i] = bs[i] + G[blockIdx.x * NB + i];
        cur[i] = 0;
    }
    __syncthreads();
    int s = blockIdx.x * EB;
    int e = min(s + EB, E);
    for (int i = s + t; i < e; i += 256) {
        int d = dst[i];
        int j = d >> BKT_SHIFT;
        int r = atomicAdd(&cur[j], 1);
        tmp[offs[j] + r] = (unsigned int)src[i] | ((unsigned int)(d & 255) << 24);
    }
}

// ---- pass 4: one block per bucket: rowptr/dinv/dsq + CSR col fill (all local)
__global__ void csr_k(const unsigned int* __restrict__ tmp, const int* __restrict__ bs,
                      int* __restrict__ rowptr, float* __restrict__ dinv,
                      float* __restrict__ dsq, int* __restrict__ col, int N, int E) {
    __shared__ int cnt[256];
    __shared__ int ptr[256];
    int j = blockIdx.x;
    int t = threadIdx.x;
    int base = j << BKT_SHIFT;
    int s = bs[j];
    int e = bs[j + 1];
    cnt[t] = 0;
    __syncthreads();
    for (int i = s + t; i < e; i += 256)
        atomicAdd(&cnt[tmp[i] >> 24], 1);
    __syncthreads();
    int v = cnt[t];
    ptr[t] = v;
    __syncthreads();
    for (int off = 1; off < 256; off <<= 1) {
        int a = (t >= off) ? ptr[t - off] : 0;
        __syncthreads();
        ptr[t] += a;
        __syncthreads();
    }
    int excl = ptr[t] - v;
    int node = base + t;
    if (node < N) {
        rowptr[node] = s + excl;
        float d = (float)(v + 1);              // +1 self-loop
        dinv[node] = rsqrtf(d);
        dsq[node] = sqrtf(d);
    }
    if (j == 0 && t == 0) rowptr[N] = E;
    cnt[t] = excl;  // cursor
    __syncthreads();
    for (int i = s + t; i < e; i += 256) {
        unsigned int p = tmp[i];
        int loc = p >> 24;
        int r = atomicAdd(&cnt[loc], 1);
        col[s + r] = (int)(p & 0xFFFFFF);
    }
}

// ---- Z0[node][40] (bf16) = dinv[node] * (x[node] @ W)
// 320 threads / 256-node tile; thread tile = 4 nodes x 8 classes.
__global__ __launch_bounds__(320) void gemm_k(const float* __restrict__ x,
                                              const float* __restrict__ W,
                                              const float* __restrict__ dinv,
                                              uint4* __restrict__ Zbf, int n) {
    __shared__ float Ws[FDIM * CDIM];   // 20 KB
    __shared__ float xT[32][257];       // 32.9 KB
    int t = threadIdx.x;
    for (int i = t; i < FDIM * CDIM; i += 320) Ws[i] = W[i];
    int base = blockIdx.x * 256;
    int cg = t >> 6;   // 0..4 (8 classes each) -> one uint4 per node
    int ng = t & 63;
    float acc[4][8];
    #pragma unroll
    for (int k = 0; k < 4; ++k)
        #pragma unroll
        for (int c = 0; c < 8; ++c) acc[k][c] = 0.f;

    for (int ch = 0; ch < 4; ++ch) {
        __syncthreads();
        for (int i = t; i < 2048; i += 320) {
            int f4 = i & 7;
            int nn = i >> 3;
            int node = base + nn;
            float4 xv = make_float4(0.f, 0.f, 0.f, 0.f);
            if (node < n)
                xv = *(const float4*)(x + (size_t)node * FDIM + ch * 32 + f4 * 4);
            xT[f4 * 4 + 0][nn] = xv.x;
            xT[f4 * 4 + 1][nn] = xv.y;
            xT[f4 * 4 + 2][nn] = xv.z;
            xT[f4 * 4 + 3][nn] = xv.w;
        }
        __syncthreads();
        for (int f = 0; f < 32; ++f) {
            float x0 = xT[f][ng];
            float x1 = xT[f][ng + 64];
            float x2 = xT[f][ng + 128];
            float x3 = xT[f][ng + 192];
            const float* wr = &Ws[(ch * 32 + f) * CDIM + cg * 8];
            float4 w0 = *(const float4*)(wr);
            float4 w1 = *(const float4*)(wr + 4);
            float wv[8] = {w0.x, w0.y, w0.z, w0.w, w1.x, w1.y, w1.z, w1.w};
            #pragma unroll
            for (int c = 0; c < 8; ++c) {
                acc[0][c] += x0 * wv[c];
                acc[1][c] += x1 * wv[c];
                acc[2][c] += x2 * wv[c];
                acc[3][c] += x3 * wv[c];
            }
        }
    }
    #pragma unroll
    for (int k = 0; k < 4; ++k) {
        int node = base + ng + 64 * k;
        if (node >= n) continue;
        float di = dinv[node];
        uint4 o;
        o.x = pack2(acc[k][0] * di, acc[k][1] * di);
        o.y = pack2(acc[k][2] * di, acc[k][3] * di);
        o.z = pack2(acc[k][4] * di, acc[k][5] * di);
        o.w = pack2(acc[k][6] * di, acc[k][7] * di);
        Zbf[(size_t)node * 5 + cg] = o;
    }
}

// ---- one hop: Zout[i] = di^2 (sum_{s->i} Zin[s] + Zin[i])
// Zin bf16 rows (5 x uint4). BF16OUT: pack bf16 (hop1) else fp32 (hop2).
template <bool BF16OUT>
__global__ __launch_bounds__(256) void prop_k(const int* __restrict__ rowptr,
                                              const int* __restrict__ col,
                                              const float* __restrict__ dinv,
                                              const uint4* __restrict__ Zin,
                                              uint4* __restrict__ Zout_bf,
                                              float* __restrict__ Zout_f32, int n) {
    int t = threadIdx.x;
    int g = t / 5;
    int c8 = t - g * 5;
    if (g >= NPB) return;
    int node = blockIdx.x * NPB + g;
    if (node >= n) return;
    float di = dinv[node];
    float acc[8];
    #pragma unroll
    for (int c = 0; c < 8; ++c) acc[c] = 0.f;
    addu4(Zin[(size_t)node * 5 + c8], acc);   // self-loop
    int e = rowptr[node];
    int end = rowptr[node + 1];
    for (; e + 3 < end; e += 4) {
        int s0 = col[e], s1 = col[e + 1], s2 = col[e + 2], s3 = col[e + 3];
        uint4 a0 = Zin[(size_t)s0 * 5 + c8];
        uint4 a1 = Zin[(size_t)s1 * 5 + c8];
        uint4 a2 = Zin[(size_t)s2 * 5 + c8];
        uint4 a3 = Zin[(size_t)s3 * 5 + c8];
        addu4(a0, acc); addu4(a1, acc); addu4(a2, acc); addu4(a3, acc);
    }
    for (; e < end; ++e) {
        addu4(Zin[(size_t)col[e] * 5 + c8], acc);
    }
    float w = di * di;
    #pragma unroll
    for (int c = 0; c < 8; ++c) acc[c] *= w;
    if (BF16OUT) {
        uint4 o;
        o.x = pack2(acc[0], acc[1]);
        o.y = pack2(acc[2], acc[3]);
        o.z = pack2(acc[4], acc[5]);
        o.w = pack2(acc[6], acc[7]);
        Zout_bf[(size_t)node * 5 + c8] = o;
    } else {
        float* p = Zout_f32 + (size_t)node * CDIM + c8 * 8;
        *(float4*)p = make_float4(acc[0], acc[1], acc[2], acc[3]);
        *(float4*)(p + 4) = make_float4(acc[4], acc[5], acc[6], acc[7]);
    }
}

// ---- final: logits = Z2[i]*dsq[i] + b; log_softmax; thread-per-node.
__global__ void final_k(const float4* __restrict__ Z, const float* __restrict__ dsq,
                        const float* __restrict__ bias, float4* __restrict__ out, int n) {
    __shared__ float bsm[CDIM];
    int t = threadIdx.x;
    if (t < CDIM) bsm[t] = bias[t];
    __syncthreads();
    int node = blockIdx.x * 256 + t;
    if (node >= n) return;
    float ds = dsq[node];
    float v[CDIM];
    #pragma unroll
    for (int c4 = 0; c4 < C4; ++c4) {
        float4 z = Z[(size_t)node * C4 + c4];
        v[c4 * 4 + 0] = z.x * ds + bsm[c4 * 4 + 0];
        v[c4 * 4 + 1] = z.y * ds + bsm[c4 * 4 + 1];
        v[c4 * 4 + 2] = z.z * ds + bsm[c4 * 4 + 2];
        v[c4 * 4 + 3] = z.w * ds + bsm[c4 * 4 + 3];
    }
    float m = v[0];
    #pragma unroll
    for (int c = 1; c < CDIM; ++c) m = fmaxf(m, v[c]);
    float s = 0.f;
    #pragma unroll
    for (int c = 0; c < CDIM; ++c) s += expf(v[c] - m);
    float ls = m + logf(s);
    #pragma unroll
    for (int c4 = 0; c4 < C4; ++c4) {
        out[(size_t)node * C4 + c4] = make_float4(
            v[c4 * 4 + 0] - ls, v[c4 * 4 + 1] - ls,
            v[c4 * 4 + 2] - ls, v[c4 * 4 + 3] - ls);
    }
}

extern "C" void kernel_launch(void* const* d_in, const int* in_sizes, int n_in,
                              void* d_out, int out_size, void* d_ws, size_t ws_size,
                              hipStream_t stream) {
    const float* x = (const float*)d_in[0];
    const float* W = (const float*)d_in[1];
    const float* b = (const float*)d_in[2];
    const int* ei = (const int*)d_in[3];

    int C = in_sizes[2];            // 40
    int F = in_sizes[1] / C;        // 128
    int N = in_sizes[0] / F;        // 100000
    int E = in_sizes[3] / 2;        // 1600000
    const int* src = ei;
    const int* dst = ei + E;

    // workspace: union region holds {G,T,bs,tmp} during build, then
    // Z0bf (8 MB, gemm out) then Zfin fp32 (16 MB, hop-2 out; Z0 dead).
    char* ws = (char*)d_ws;
    size_t goff = 0;
    int* G = (int*)(ws + goff);                       goff += (size_t)NBLK * NB * 4;
    int* T = (int*)(ws + goff);                       goff += (size_t)NB * 4;
    int* bs = (int*)(ws + goff);                      goff += (size_t)(NB + 1) * 4 + 12;
    goff = (goff + 15) & ~(size_t)15;
    unsigned int* tmp = (unsigned int*)(ws + goff);   goff += (size_t)E * 4;
    size_t unionEnd = ((size_t)N * CDIM * 4 > goff) ? (size_t)N * CDIM * 4 : goff;
    unionEnd = (unionEnd + 15) & ~(size_t)15;
    uint4* Z0bf = (uint4*)ws;        // 8 MB, overlays build scratch
    float* Zfin = (float*)ws;        // 16 MB, overlays Z0bf (dead at hop 2)
    size_t off = unionEnd;
    int* rowptr = (int*)(ws + off); off += ((size_t)(N + 1) * 4 + 15) & ~(size_t)15;
    float* dinv = (float*)(ws + off); off += ((size_t)N * 4 + 15) & ~(size_t)15;
    float* dsq = (float*)(ws + off); off += ((size_t)N * 4 + 15) & ~(size_t)15;
    int* col = (int*)(ws + off); off += ((size_t)E * 4 + 15) & ~(size_t)15;
    uint4* Zb = (uint4*)d_out;       // hop-1 bf16 out (first 8 MB of d_out)

    int EB = (E + NBLK - 1) / NBLK;
    int NBr = (N + 255) >> BKT_SHIFT;

    hist_k<<<NBLK, 256, 0, stream>>>(dst, G, E, EB);
    colscan_k<<<NB, 256, 0, stream>>>(G, T);
    bscan_k<<<1, 256, 0, stream>>>(T, bs);
    part_k<<<NBLK, 256, 0, stream>>>(src, dst, G, bs, tmp, E, EB);
    csr_k<<<NBr, 256, 0, stream>>>(tmp, bs, rowptr, dinv, dsq, col, N, E);

    gemm_k<<<(N + 255) / 256, 320, 0, stream>>>(x, W, dinv, Z0bf, N);

    int pgrid = (N + NPB - 1) / NPB;
    prop_k<true><<<pgrid, 256, 0, stream>>>(rowptr, col, dinv, Z0bf, Zb, nullptr, N);
    prop_k<false><<<pgrid, 256, 0, stream>>>(rowptr, col, dinv, Zb, nullptr, Zfin, N);

    final_k<<<(N + 255) / 256, 256, 0, stream>>>((const float4*)Zfin, dsq, b,
                                                 (float4*)d_out, N);
}